// Round 8
// baseline (3564.333 us; speedup 1.0000x reference)
//
#include <hip/hip_runtime.h>
#include <hip/hip_bf16.h>

// B=256, L=2048, H=128, V=32000, THR=0.4, LN_EPS=1e-5. All fp32.
// Htab2 row (RS=136 float stride, PLAIN layout): [0:128)=h, [128]=kk, [129]=inv.
// Scan v8: ONE WAVE PER BATCH (block=128 = 2 independent waves, grid=128).
// Lane owns rows {2l, 2l+1} of M in 256 VGPRs. k read per step via uniform
// broadcast ds_read_b128 from a wave-private 4-slot LDS ring (global_load_lds,
// vmcnt(2) discipline). No barriers anywhere in the scan. Gate = DPP tree +
// readlane + wave-uniform branch; update skipped when gate off.

#define BB 256
#define LL 2048
#define HH 128
#define VV 32000
#define RS 136
#define WSS 256   // slot stride in floats (1 KB: full-wave DMA writes 64*16B)

typedef float f32x2 __attribute__((ext_vector_type(2)));

__device__ __forceinline__ void dma16(const float* g, float* l) {
  __builtin_amdgcn_global_load_lds(
      (const __attribute__((address_space(1))) void*)g,
      (__attribute__((address_space(3))) void*)l,
      16, 0, 0);
}

template <int CTRL>
__device__ __forceinline__ float dppadd(float x) {
  int y = __builtin_amdgcn_update_dpp(0, __float_as_int(x), CTRL, 0xF, 0xF, true);
  return x + __int_as_float(y);
}

__device__ __forceinline__ void pkfma(f32x2& d, f32x2 a, f32x2 b) {
  asm("v_pk_fma_f32 %0, %1, %2, %0" : "+v"(d) : "v"(a), "v"(b));
}

__device__ __forceinline__ void wait_vm0() {
  asm volatile("s_waitcnt vmcnt(0)" ::: "memory");
}
__device__ __forceinline__ void wait_vm2() {
  asm volatile("s_waitcnt vmcnt(2)" ::: "memory");
}
__device__ __forceinline__ void wait_lgkm0() {
  asm volatile("s_waitcnt lgkmcnt(0)" ::: "memory");
}

// ---------------------------------------------------------------------------
// Kernel A: Htab2 row = LN(e + relu(e@W1+b1)@W2 + b2) (+ kk, inv). PLAIN layout.
// ---------------------------------------------------------------------------
__global__ __launch_bounds__(256, 1) void build_htab_kernel(
    const float* __restrict__ embed,
    const float* __restrict__ W1,
    const float* __restrict__ b1,
    const float* __restrict__ W2,
    const float* __restrict__ b2,
    const float* __restrict__ gamma,
    const float* __restrict__ beta,
    float* __restrict__ Htab2)
{
  const int tid = threadIdx.x;
  const int j   = tid & 127;
  const int h2  = tid >> 7;

  float w1r[128];
#pragma unroll
  for (int m = 0; m < 128; ++m) w1r[m] = W1[m * 256 + tid];

  const float b1n = b1[tid];
  const float b2j = b2[j];
  const float gj  = gamma[j];
  const float bj  = beta[j];

  __shared__ __align__(16) float4 w2q[64][128];
  __shared__ __align__(16) float e_s[128];
  __shared__ __align__(16) float a_s[256];
  __shared__ float p_s[2][128];
  __shared__ float red[8];

  for (int idx = tid; idx < 8192; idx += 256) {
    int n4 = idx >> 7, jj = idx & 127;
    float4 w;
    w.x = W2[(size_t)(4 * n4 + 0) * 128 + jj];
    w.y = W2[(size_t)(4 * n4 + 1) * 128 + jj];
    w.z = W2[(size_t)(4 * n4 + 2) * 128 + jj];
    w.w = W2[(size_t)(4 * n4 + 3) * 128 + jj];
    w2q[n4][jj] = w;
  }
  __syncthreads();

  for (int v = blockIdx.x; v < VV; v += gridDim.x) {
    if (tid < 128) e_s[tid] = embed[(size_t)v * 128 + tid];
    __syncthreads();

    float acc[4] = {b1n, 0.f, 0.f, 0.f};
#pragma unroll
    for (int q = 0; q < 32; ++q) {
      float4 ev = *(const float4*)&e_s[4 * q];
      float t = ev.x * w1r[4 * q + 0];
      t = fmaf(ev.y, w1r[4 * q + 1], t);
      t = fmaf(ev.z, w1r[4 * q + 2], t);
      t = fmaf(ev.w, w1r[4 * q + 3], t);
      acc[q & 3] += t;
    }
    float a = fmaxf((acc[0] + acc[1]) + (acc[2] + acc[3]), 0.0f);
    a_s[tid] = a;
    __syncthreads();

    float p0 = 0.f, p1 = 0.f, p2v = 0.f, p3 = 0.f;
#pragma unroll
    for (int q = 0; q < 32; ++q) {
      int n4 = h2 * 32 + q;
      float4 av = *(const float4*)&a_s[4 * n4];
      float4 wq = w2q[n4][j];
      p0 = fmaf(av.x, wq.x, p0);
      p1 = fmaf(av.y, wq.y, p1);
      p2v = fmaf(av.z, wq.z, p2v);
      p3 = fmaf(av.w, wq.w, p3);
    }
    p_s[h2][j] = (p0 + p1) + (p2v + p3);
    __syncthreads();

    float y = 0.0f;
    if (tid < 128) {
      float ff = p_s[0][tid] + p_s[1][tid] + b2j;
      y = e_s[tid] + ff;
    }
    float s1 = y, s2 = y * y;
    s1 = dppadd<0xB1>(s1);  s2 = dppadd<0xB1>(s2);
    s1 = dppadd<0x4E>(s1);  s2 = dppadd<0x4E>(s2);
    s1 = dppadd<0x141>(s1); s2 = dppadd<0x141>(s2);
    s1 = dppadd<0x140>(s1); s2 = dppadd<0x140>(s2);
    s1 = dppadd<0x142>(s1); s2 = dppadd<0x142>(s2);
    s1 = dppadd<0x143>(s1); s2 = dppadd<0x143>(s2);
    if (tid < 128 && (tid & 63) == 63) {
      red[tid >> 6] = s1;
      red[2 + (tid >> 6)] = s2;
    }
    __syncthreads();
    float mu = (red[0] + red[1]) * (1.0f / 128.0f);
    float ms = (red[2] + red[3]) * (1.0f / 128.0f);
    float var = ms - mu * mu;
    float hv = 0.0f;
    if (tid < 128) {
      float dy = y - mu;
      hv = dy * (1.0f / sqrtf(var + 1e-5f)) * gj + bj;
      Htab2[(size_t)v * RS + tid] = hv;       // plain layout
    }
    float q2 = hv * hv;
    q2 = dppadd<0xB1>(q2);
    q2 = dppadd<0x4E>(q2);
    q2 = dppadd<0x141>(q2);
    q2 = dppadd<0x140>(q2);
    q2 = dppadd<0x142>(q2);
    q2 = dppadd<0x143>(q2);
    if (tid < 128 && (tid & 63) == 63) red[4 + (tid >> 6)] = q2;
    __syncthreads();
    if (tid == 0) {
      float kk = red[4] + red[5];
      Htab2[(size_t)v * RS + 128] = kk;
      Htab2[(size_t)v * RS + 129] = 1.0f / (kk + 1e-6f);
    }
    __syncthreads();
  }
}

// ---------------------------------------------------------------------------
// Kernel B: one wave per batch. 128 blocks x 128 threads (2 waves/block).
// ---------------------------------------------------------------------------
__global__ __launch_bounds__(128, 1) void scan_kernel(
    const int* __restrict__ seq,
    const float* __restrict__ Htab2,
    const float* __restrict__ Wrp,
    const float* __restrict__ brp,
    float* __restrict__ rr)
{
  const int tid  = threadIdx.x;
  const int lane = tid & 63;
  const int wv   = tid >> 6;
  const int b    = blockIdx.x * 2 + wv;

  __shared__ int seq_s[2][LL];
  __shared__ __align__(16) float slots[2][4][WSS];
  __shared__ __align__(16) float rbuf[2][128];

  int*   sq   = seq_s[wv];
  float* slot = &slots[wv][0][0];

  for (int i = lane; i < LL; i += 64) sq[i] = seq[(size_t)b * LL + i];

  {  // prologue DMAs: k0 -> ring slot 0, k1 -> ring slot 1
    int t0 = seq[(size_t)b * LL + 0];
    int t1 = seq[(size_t)b * LL + 1];
    dma16(Htab2 + (size_t)t0 * RS + lane * 4, slot);
    dma16(Htab2 + (size_t)t1 * RS + lane * 4, slot + WSS);
  }
  wait_vm0();
  wait_lgkm0();   // seq_s staged (cross-lane reads follow)

  f32x2 m0[64], m1[64];   // rows 2*lane, 2*lane+1 as 64 col-pairs each
#pragma unroll
  for (int c = 0; c < 64; ++c) {
    m0[c] = f32x2{0.f, 0.f};
    m1[c] = f32x2{0.f, 0.f};
  }

  for (int t = 0; t < LL - 1; ++t) {       // 2047 steps, zero barriers
    int tn = t + 2; if (tn > LL - 1) tn = LL - 1;
    int tok = sq[tn];
    dma16(Htab2 + (size_t)tok * RS + lane * 4, slot + ((t + 2) & 3) * WSS);
    wait_vm2();                             // k_t (DMA'd 2 steps ago) landed
    asm volatile("" ::: "memory");

    const float*  sl = slot + (t & 3) * WSS;
    const float4* kp = (const float4*)sl;
    f32x2 kown = *(const f32x2*)(sl + 2 * lane);   // per-lane b64
    float kk  = sl[128];
    float inv = sl[129];

    f32x2 a00{0.f,0.f}, a01{0.f,0.f}, a10{0.f,0.f}, a11{0.f,0.f};
#pragma unroll
    for (int c = 0; c < 32; ++c) {
      float4 kq = kp[c];                    // uniform-addr broadcast b128
      f32x2 kA{kq.x, kq.y}, kB{kq.z, kq.w};
      pkfma(a00, m0[2 * c],     kA);
      pkfma(a01, m0[2 * c + 1], kB);
      pkfma(a10, m1[2 * c],     kA);
      pkfma(a11, m1[2 * c + 1], kB);
    }
    float vp0 = (a00.x + a00.y) + (a01.x + a01.y);
    float vp1 = (a10.x + a10.y) + (a11.x + a11.y);
    float e0 = fmaf(-vp0, inv, kown.x);
    float e1 = fmaf(-vp1, inv, kown.y);
    float s = fmaf(e0, e0, e1 * e1);        // rows distinct across lanes
    s = dppadd<0xB1>(s);                    // full 6-level tree -> lane 63
    s = dppadd<0x4E>(s);
    s = dppadd<0x141>(s);
    s = dppadd<0x140>(s);
    s = dppadd<0x142>(s);
    s = dppadd<0x143>(s);
    float ne2 = __int_as_float(__builtin_amdgcn_readlane(__float_as_int(s), 63));
    if (ne2 > 0.16f * kk) {                 // wave-uniform branch
      f32x2 ev0{e0, e0}, ev1{e1, e1};
#pragma unroll
      for (int c = 0; c < 32; ++c) {
        float4 kq = kp[c];
        f32x2 kA{kq.x, kq.y}, kB{kq.z, kq.w};
        pkfma(m0[2 * c],     ev0, kA);
        pkfma(m0[2 * c + 1], ev0, kB);
        pkfma(m1[2 * c],     ev1, kA);
        pkfma(m1[2 * c + 1], ev1, kB);
      }
    }
  }

  wait_vm0();
  // r rows for this lane with k_2047 (ring slot 3)
  {
    const float*  sl = slot + ((LL - 1) & 3) * WSS;
    const float4* kp = (const float4*)sl;
    f32x2 a00{0.f,0.f}, a01{0.f,0.f}, a10{0.f,0.f}, a11{0.f,0.f};
#pragma unroll
    for (int c = 0; c < 32; ++c) {
      float4 kq = kp[c];
      f32x2 kA{kq.x, kq.y}, kB{kq.z, kq.w};
      pkfma(a00, m0[2 * c],     kA);
      pkfma(a01, m0[2 * c + 1], kB);
      pkfma(a10, m1[2 * c],     kA);
      pkfma(a11, m1[2 * c + 1], kB);
    }
    float vp0 = (a00.x + a00.y) + (a01.x + a01.y);
    float vp1 = (a10.x + a10.y) + (a11.x + a11.y);
    ((f32x2*)rbuf[wv])[lane] = f32x2{vp0, vp1};
  }
  wait_lgkm0();   // rbuf visible across lanes (same wave, in-order DS)

  // rr[b, 2l..2l+1] = r @ Wrp + brp
  f32x2 acc{0.f, 0.f};
  const float4* rbp = (const float4*)rbuf[wv];
#pragma unroll 8
  for (int m4 = 0; m4 < 32; ++m4) {
    float4 rq = rbp[m4];
    const float* wp = &Wrp[(size_t)(4 * m4) * 128 + 2 * lane];
    f32x2 w0 = *(const f32x2*)(wp);
    f32x2 w1 = *(const f32x2*)(wp + 128);
    f32x2 w2 = *(const f32x2*)(wp + 256);
    f32x2 w3 = *(const f32x2*)(wp + 384);
    pkfma(acc, w0, f32x2{rq.x, rq.x});
    pkfma(acc, w1, f32x2{rq.y, rq.y});
    pkfma(acc, w2, f32x2{rq.z, rq.z});
    pkfma(acc, w3, f32x2{rq.w, rq.w});
  }
  f32x2 bp = *(const f32x2*)&brp[2 * lane];
  f32x2 res; res.x = acc.x + bp.x; res.y = acc.y + bp.y;
  *(f32x2*)&rr[(size_t)b * 128 + 2 * lane] = res;
}

// ---------------------------------------------------------------------------
// Kernel C (unchanged)
// ---------------------------------------------------------------------------
__global__ __launch_bounds__(256, 1) void out_kernel(
    const float* __restrict__ rr,
    const float* __restrict__ Wout,
    const float* __restrict__ bout,
    float* __restrict__ out)
{
  const int tid = threadIdx.x;
  const int v = blockIdx.x * 64 + (tid & 63);
  const int bg = tid >> 6;
  const int b0 = blockIdx.y * 64;

  __shared__ float4 rs4[64][32];
  for (int idx = tid; idx < 2048; idx += 256) {
    int bb = idx >> 5, q = idx & 31;
    rs4[bb][q] = ((const float4*)rr)[(size_t)(b0 + bb) * 32 + q];
  }
  __syncthreads();

  float acc[16];
#pragma unroll
  for (int m = 0; m < 16; ++m) acc[m] = 0.0f;

  for (int h4 = 0; h4 < 32; ++h4) {
    float w0 = Wout[(size_t)(4 * h4 + 0) * VV + v];
    float w1 = Wout[(size_t)(4 * h4 + 1) * VV + v];
    float w2 = Wout[(size_t)(4 * h4 + 2) * VV + v];
    float w3 = Wout[(size_t)(4 * h4 + 3) * VV + v];
#pragma unroll
    for (int m = 0; m < 16; ++m) {
      float4 rv = rs4[bg * 16 + m][h4];
      float t = rv.x * w0;
      t = fmaf(rv.y, w1, t);
      t = fmaf(rv.z, w2, t);
      t = fmaf(rv.w, w3, t);
      acc[m] += t;
    }
  }
  float bo = bout[v];
#pragma unroll
  for (int m = 0; m < 16; ++m) {
    out[(size_t)(b0 + bg * 16 + m) * VV + v] = acc[m] + bo;
  }
}

// ---------------------------------------------------------------------------
extern "C" void kernel_launch(void* const* d_in, const int* in_sizes, int n_in,
                              void* d_out, int out_size, void* d_ws, size_t ws_size,
                              hipStream_t stream)
{
  const int* seq      = (const int*)d_in[0];
  const float* embed  = (const float*)d_in[1];
  const float* W1     = (const float*)d_in[2];
  const float* b1     = (const float*)d_in[3];
  const float* W2     = (const float*)d_in[4];
  const float* b2     = (const float*)d_in[5];
  const float* gamma  = (const float*)d_in[6];
  const float* beta   = (const float*)d_in[7];
  const float* Wrp    = (const float*)d_in[8];
  const float* brp    = (const float*)d_in[9];
  const float* Wout   = (const float*)d_in[10];
  const float* bout   = (const float*)d_in[11];
  float* out          = (float*)d_out;

  char* ws = (char*)d_ws;
  float* Htab2 = (float*)ws;                         // 32000*136*4 = 17,408,000 B
  float* rr    = (float*)(ws + 17412096);            // +4KB pad (OOB DMA tail)

  hipLaunchKernelGGL(build_htab_kernel, dim3(256), dim3(256), 0, stream,
                     embed, W1, b1, W2, b2, gamma, beta, Htab2);
  hipLaunchKernelGGL(scan_kernel, dim3(BB / 2), dim3(128), 0, stream,
                     seq, Htab2, Wrp, brp, rr);
  hipLaunchKernelGGL(out_kernel, dim3(VV / 64, 4), dim3(256), 0, stream,
                     rr, Wout, bout, out);
}